// Round 7
// baseline (497.676 us; speedup 1.0000x reference)
//
#include <hip/hip_runtime.h>
#include <math.h>

#define NTRAIN 2000
#define DIMD 210
#define DIMI 63
#define NPERM 12
#define NCOLS 8
#define NATOM 21
#define SIGF 10.0f

// ws layout (ints):
#define WS_PERM      0        // 2520
#define WS_GTAB      6300     // 5040
#define WS_ENTOFF    11340    // 442
#define WS_ENTS      11782    // 10080
#define WS_TILEMAP   21862    // 441
// total 22303 ints (~89 KB)

// ---------------- setup: fully parallel, LDS-staged (~20us) ----------------
__global__ __launch_bounds__(512) void gdml_setup(const int* __restrict__ tril,
                                                  int* __restrict__ ws) {
  __shared__ int sPerm[NPERM * DIMD];
  __shared__ int sInv[NPERM * DIMD];
  __shared__ int sRow[DIMD], sCol[DIMD];
  __shared__ int sPairs[NATOM * 20], sNeg[NATOM * 20];
  __shared__ int sCnt[441];
  __shared__ int sScan[512];
  __shared__ int sOff[442];

  const int tid = threadIdx.x;

  for (int d = tid; d < DIMD; d += 512) {
    int a = 1;
    while ((a * (a + 1)) / 2 <= d) a++;
    sRow[d] = a;
    sCol[d] = d - (a * (a - 1)) / 2;
  }
  for (int idx = tid; idx < NPERM * DIMD; idx += 512) {
    int p = idx / DIMD, d = idx % DIMD;
    sPerm[idx] = tril[d * NPERM + p] % DIMD;
  }
  __syncthreads();
  for (int idx = tid; idx < NPERM * DIMD; idx += 512) {
    int p = idx / DIMD;
    sInv[p * DIMD + sPerm[idx]] = idx % DIMD;
  }
  if (tid < NATOM) {
    int t = tid, c = 0;
    for (int d = 0; d < DIMD; ++d) {
      if (sRow[d] == t)      { sPairs[t * 20 + c] = d; sNeg[t * 20 + c] = 0; c++; }
      else if (sCol[d] == t) { sPairs[t * 20 + c] = d; sNeg[t * 20 + c] = 1; c++; }
    }
  }
  __syncthreads();

  for (int idx = tid; idx < NPERM * DIMD; idx += 512) ws[WS_PERM + idx] = sPerm[idx];
  // gtab[(p*21+at)*20+i] = d | tw<<9 | neg<<18
  for (int idx = tid; idx < NPERM * NATOM * 20; idx += 512) {
    int p = idx / (NATOM * 20);
    int r = idx % (NATOM * 20);
    int d = sPairs[r], neg = sNeg[r];
    int tw = sInv[p * DIMD + d];
    ws[WS_GTAB + idx] = d | (tw << 9) | (neg << 18);
  }

  // CSR counts per (A,B)
  for (int q = tid; q < 441; q += 512) {
    int A = q / NATOM, B = q % NATOM, c = 0;
    for (int i = 0; i < 20; ++i) {
      int d = sPairs[A * 20 + i];
      for (int p = 0; p < NPERM; ++p) {
        int dd = sPerm[p * DIMD + d];
        c += (sRow[dd] == B) + (sCol[dd] == B);
      }
    }
    sCnt[q] = c;
  }
  __syncthreads();

  // Hillis-Steele scan over 441
  sScan[tid] = (tid < 441) ? sCnt[tid] : 0;
  __syncthreads();
  for (int s = 1; s < 512; s <<= 1) {
    int v = (tid >= s) ? sScan[tid - s] : 0;
    __syncthreads();
    sScan[tid] += v;
    __syncthreads();
  }
  if (tid == 0) sOff[0] = 0;
  if (tid < 441) sOff[tid + 1] = sScan[tid];
  __syncthreads();
  for (int q = tid; q < 442; q += 512) ws[WS_ENTOFF + q] = sOff[q];

  // tileMap: rank tiles by entry count DESC (stable) for wave balance
  for (int q = tid; q < 441; q += 512) {
    int c = sCnt[q], r = 0;
    for (int q2 = 0; q2 < 441; ++q2) {
      int c2v = sCnt[q2];
      r += (c2v > c) || (c2v == c && q2 < q);
    }
    ws[WS_TILEMAP + r] = q;
  }

  // fill entries: v = d | dd<<9 | p<<18 | negbit<<22 (negbit=1 -> coef = -c2)
  for (int q = tid; q < 441; q += 512) {
    int A = q / NATOM, B = q % NATOM;
    int o = sOff[q];
    for (int i = 0; i < 20; ++i) {
      int d = sPairs[A * 20 + i];
      int negA = sNeg[A * 20 + i];
      for (int p = 0; p < NPERM; ++p) {
        int dd = sPerm[p * DIMD + d];
        int base = d | (dd << 9) | (p << 18);
        if (sRow[dd] == B) ws[WS_ENTS + (o++)] = base | ((negA ^ 1) << 22);
        if (sCol[dd] == B) ws[WS_ENTS + (o++)] = base | (negA << 22);
      }
    }
  }
}

// ---------------- main kernel: one block per (n, j-column) ----------------
__global__ __launch_bounds__(256, 4) void gdml_main(
    const float* __restrict__ R_desc, const float* __restrict__ R_d_desc,
    const int* __restrict__ j_idxs, const int* __restrict__ ws,
    float* __restrict__ out) {
  const int* perm    = ws + WS_PERM;
  const int* gtab    = ws + WS_GTAB;
  const int* entOff  = ws + WS_ENTOFF;
  const int* ents    = ws + WS_ENTS;
  const int* tileMap = ws + WS_TILEMAP;

  const int bid = blockIdx.x;
  const int jc = bid & 7;
  const int n = bid >> 3;
  const int tid = threadIdx.x;
  const int j = j_idxs[jc];

  __shared__ __align__(16) float diffS[NPERM][DIMD];           // 10,080 B
  __shared__ __align__(16) float4 Rdn4[DIMD];                  // 3,360 (b128 gathers)
  __shared__ __align__(16) float4 Rdj4[DIMD];                  // 3,360
  __shared__ float Rn[DIMD], Rj[DIMD];                         // 1,680
  __shared__ __align__(16) float GT[NPERM][64], bT[NPERM][64]; // 6,144 (p-major)
  __shared__ float c1s[NPERM], c2s[NPERM];
  __shared__ float partial[252];
  // ~25.7 KB -> 6 blocks/CU

  // ---- stage inputs ----
  for (int i = tid; i < DIMD; i += 256) {
    Rn[i] = R_desc[(size_t)n * DIMD + i];
    Rj[i] = R_desc[(size_t)j * DIMD + i];
  }
  if (tid < DIMD) {
    const float* gn = R_d_desc + (size_t)n * (DIMD * 3) + 3 * tid;
    const float* gj = R_d_desc + (size_t)j * (DIMD * 3) + 3 * tid;
    Rdn4[tid] = make_float4(gn[0], gn[1], gn[2], 0.f);
    Rdj4[tid] = make_float4(gj[0], gj[1], gj[2], 0.f);
  }
  __syncthreads();

  // ---- diff[p][d] = Rn[d] - Rj[perm[p][d]] ----
  for (int idx = tid; idx < NPERM * DIMD; idx += 256) {
    int d = idx % DIMD;
    ((float*)diffS)[idx] = Rn[d] - Rj[perm[idx]];
  }
  __syncthreads();

  // ---- norms ----
  if (tid < 252) {
    int p = tid / 21, seg = tid % 21;
    const float* dp = &diffS[p][seg * 10];
    float s = 0.f;
#pragma unroll
    for (int i = 0; i < 10; ++i) s += dp[i] * dp[i];
    partial[tid] = s;
  }
  __syncthreads();
  if (tid < NPERM) {
    float s = 0.f;
#pragma unroll
    for (int i = 0; i < 21; ++i) s += partial[tid * 21 + i];
    float nrm = sqrtf(5.0f) * sqrtf(s);
    float mat52 = expf(-nrm / SIGF) * (5.0f / (3.0f * SIGF * SIGF * SIGF * SIGF));
    c1s[tid] = 5.0f * mat52;
    c2s[tid] = (SIGF * SIGF + SIGF * nrm) * mat52;
  }
  __syncthreads();

  // ---- b/G: thread = (p, at); sign via bit-XOR; operands via b128 ----
  if (tid < NPERM * NATOM) {
    int p = tid / NATOM, at = tid % NATOM;
    const int* gt = &gtab[(p * NATOM + at) * 20];
    const float* dfp = &diffS[p][0];
    float g0 = 0, g1 = 0, g2 = 0, b0 = 0, b1 = 0, b2 = 0;
#pragma unroll
    for (int i = 0; i < 20; ++i) {
      int v = gt[i];
      int d = v & 511, tw = (v >> 9) & 511;
      unsigned sg = ((unsigned)(v & (1 << 18))) << 13;  // bit18 -> bit31
      float fd = __uint_as_float(__float_as_uint(dfp[d]) ^ sg);
      float ftw = __uint_as_float(__float_as_uint(dfp[tw]) ^ sg);
      float4 rn = Rdn4[d];
      float4 rj = Rdj4[d];
      g0 += rn.x * fd; g1 += rn.y * fd; g2 += rn.z * fd;
      b0 += rj.x * ftw; b1 += rj.y * ftw; b2 += rj.z * ftw;
    }
    float c1 = c1s[p];
    GT[p][3 * at + 0] = c1 * g0;
    GT[p][3 * at + 1] = c1 * g1;
    GT[p][3 * at + 2] = c1 * g2;
    bT[p][3 * at + 0] = b0;
    bT[p][3 * at + 1] = b1;
    bT[p][3 * at + 2] = b2;
  }
  __syncthreads();

  // ---- final: rank-sorted (A,B) 3x3 tiles; b128 operand reads ----
  const size_t base = (size_t)n * DIMI * (NCOLS * DIMI) + (size_t)jc * DIMI;
#pragma unroll
  for (int pass = 0; pass < 2; ++pass) {
    int rank = tid + pass * 256;
    if (rank < NATOM * NATOM) {
      int q = tileMap[rank];
      int A = q / NATOM, B = q % NATOM;
      float acc[3][3];
#pragma unroll
      for (int c = 0; c < 3; ++c)
#pragma unroll
        for (int e = 0; e < 3; ++e) acc[c][e] = 0.f;

      // term2: acc += (+/-)c2[p] * Rdn[d,:] (x) Rdj[dd,:]
      int o0 = entOff[q], o1 = entOff[q + 1];
      for (int o = o0; o < o1; ++o) {
        int v = ents[o];
        int d = v & 511, dd = (v >> 9) & 511, p = (v >> 18) & 15;
        unsigned sgn = ((unsigned)(v & (1 << 22))) << 9;  // bit22 -> bit31
        float c2 = __uint_as_float(__float_as_uint(c2s[p]) ^ sgn);
        float4 rn = Rdn4[d];
        float4 rj = Rdj4[dd];
        float w0 = c2 * rj.x, w1 = c2 * rj.y, w2 = c2 * rj.z;
        acc[0][0] += rn.x * w0; acc[0][1] += rn.x * w1; acc[0][2] += rn.x * w2;
        acc[1][0] += rn.y * w0; acc[1][1] += rn.y * w1; acc[1][2] += rn.y * w2;
        acc[2][0] += rn.z * w0; acc[2][1] += rn.z * w1; acc[2][2] += rn.z * w2;
      }

      // term1: acc[cg][cb] += sum_p GT[p][3A+cg] * bT[p][3B+cb]
#pragma unroll
      for (int p = 0; p < NPERM; ++p) {
        float ga = GT[p][3 * A + 0], gb = GT[p][3 * A + 1], gc = GT[p][3 * A + 2];
        float ba = bT[p][3 * B + 0], bb = bT[p][3 * B + 1], bc = bT[p][3 * B + 2];
        acc[0][0] += ga * ba; acc[0][1] += ga * bb; acc[0][2] += ga * bc;
        acc[1][0] += gb * ba; acc[1][1] += gb * bb; acc[1][2] += gb * bc;
        acc[2][0] += gc * ba; acc[2][1] += gc * bb; acc[2][2] += gc * bc;
      }

#pragma unroll
      for (int cg = 0; cg < 3; ++cg) {
        float* op = out + base + (size_t)(3 * A + cg) * (NCOLS * DIMI) + 3 * B;
        op[0] = acc[cg][0]; op[1] = acc[cg][1]; op[2] = acc[cg][2];
      }
    }
  }
}

extern "C" void kernel_launch(void* const* d_in, const int* in_sizes, int n_in,
                              void* d_out, int out_size, void* d_ws, size_t ws_size,
                              hipStream_t stream) {
  const float* R_desc = (const float*)d_in[0];
  const float* R_d_desc = (const float*)d_in[1];
  const int* tril = (const int*)d_in[2];
  const int* j_idxs = (const int*)d_in[3];
  float* out = (float*)d_out;
  int* ws = (int*)d_ws;

  hipLaunchKernelGGL(gdml_setup, dim3(1), dim3(512), 0, stream, tril, ws);
  hipLaunchKernelGGL(gdml_main, dim3(NTRAIN * NCOLS), dim3(256), 0, stream,
                     R_desc, R_d_desc, j_idxs, ws, out);
}